// Round 12
// baseline (77.310 us; speedup 1.0000x reference)
//
#include <hip/hip_runtime.h>
#include <hip/hip_bf16.h>

// EdgeConv: B=8, C=64, N=4096, K=16, O=64
// out[n] = relu(F[n] + max_k G[src[n,k]]);  F = x@(Wa-Wb)+bias, G = x@Wb.
//
// Single-dispatch XCD-self-scheduled design (R6..R11 coherence evidence):
//  - Cross-dispatch gathers are pinned at L3 speed when correct (per-XCD L2s are
//    invalidated/flushed at dispatch boundaries; thrash is what made R8/R9/R11 correct).
//  - Same-dispatch, same-XCD producer->consumer keeps FG dirty in the LOCAL L2:
//    correct by construction (no coherence crossing) and L2-fast (R6's 6.8us replay).
//  - Each block reads its physical XCD (s_getreg HW_REG_XCC_ID, m09-verified) and
//    work-steals batch xcc's tiles via device-scope atomics (m20-verified coherent).
//  - NO __threadfence (R7/R10: 60-85us). Counters zeroed via hipMemsetAsync per call.
//  - Replay residue is benign: deterministic values -> stale-clean == fresh; the one
//    differing epoch (0xAA poison) is write-hit-overwritten locally before any read.

#define BB 8
#define CC 64
#define NN 4096
#define KK 16
#define OO 64

typedef __bf16 bf16x8 __attribute__((ext_vector_type(8)));
typedef float f32x4 __attribute__((ext_vector_type(4)));

union Frag { int4 i; bf16x8 v; };
union PackA { bf16x8 v; __hip_bfloat16 h[8]; };

static constexpr size_t FG_BYTES = (size_t)BB * NN * 128 * 2;   // 8 MB bf16
static constexpr int GRID = 512;                                // <=2/CU -> co-resident

__global__ __launch_bounds__(256, 2) void edgeconv_xcd(
    const float* __restrict__ x, const int* __restrict__ ei,
    const float* __restrict__ W, const float* __restrict__ bias,
    float* __restrict__ out, __hip_bfloat16* __restrict__ FG,
    unsigned* __restrict__ ctr) {
    __shared__ union {
        struct { float xt[64][65]; int4 wfl[16][64]; } p;   // producer: 33 KB
        float ot[64][33];                                   // consumer: 8.4 KB
    } sm;
    __shared__ unsigned s_t;

    int t = threadIdx.x, w = t >> 6, l = t & 63;
    unsigned xreg;
    asm volatile("s_getreg_b32 %0, hwreg(HW_REG_XCC_ID)" : "=s"(xreg));
    int b = (int)(xreg & 7);              // this block's XCD == its batch

    unsigned* prod_ctr  = ctr;            // [8] producer tile tickets
    unsigned* prod_done = ctr + 8;        // [8] producer tiles completed
    unsigned* cons_ctr  = ctr + 16;       // [8] consumer tile tickets

    // ---- W fragments: build once in LDS, keep in regs ----
    {
        __hip_bfloat16* wlu = (__hip_bfloat16*)sm.p.wfl;
        int o = t & 63, h = t >> 6;
        #pragma unroll
        for (int kk = 0; kk < 16; ++kk) {
            int k = h * 16 + kk;
            float wa = W[k * OO + o];
            float wb = W[(64 + k) * OO + o];
            int g = (k >> 3) & 3, j = k & 7, ks = k >> 5;
            int lane = (g << 4) | (o & 15);
            int fsA = ks * 8 + (o >> 4);
            int fsB = fsA + 4;
            wlu[((fsA * 64 + lane) << 3) | j] = __float2bfloat16(wa - wb);
            wlu[((fsB * 64 + lane) << 3) | j] = __float2bfloat16(wb);
        }
    }
    __syncthreads();
    Frag wf[2][8];
    #pragma unroll
    for (int ks = 0; ks < 2; ++ks)
        #pragma unroll
        for (int ot = 0; ot < 8; ++ot)
            wf[ks][ot].i = sm.p.wfl[ks * 8 + ot][l];
    float bvv[8];
    #pragma unroll
    for (int ot = 0; ot < 8; ++ot) bvv[ot] = (ot < 4) ? bias[ot * 16 + (l & 15)] : 0.0f;

    const float* xb = x + (size_t)b * CC * NN;
    __hip_bfloat16* FGb = FG + (size_t)b * NN * 128;

    // ================= producer: batch b's FG, tiles of 64 nodes =================
    for (;;) {
        __syncthreads();
        if (t == 0) s_t = atomicAdd(&prod_ctr[b], 1u);
        __syncthreads();
        unsigned tt = s_t;
        if (tt >= 64u) break;
        int n0 = (int)tt << 6;

        #pragma unroll
        for (int it = 0; it < 4; ++it) {
            int idx = it * 256 + t, c = idx >> 4, q = idx & 15;
            float4 v = *(const float4*)(xb + (size_t)c * NN + n0 + q * 4);
            sm.p.xt[c][q * 4 + 0] = v.x; sm.p.xt[c][q * 4 + 1] = v.y;
            sm.p.xt[c][q * 4 + 2] = v.z; sm.p.xt[c][q * 4 + 3] = v.w;
        }
        __syncthreads();

        f32x4 acc[8];
        #pragma unroll
        for (int ot = 0; ot < 8; ++ot) acc[ot] = f32x4{bvv[ot], bvv[ot], bvv[ot], bvv[ot]};
        int node = (w << 4) + (l & 15);
        #pragma unroll
        for (int ks = 0; ks < 2; ++ks) {
            PackA a;
            #pragma unroll
            for (int j = 0; j < 8; ++j)
                a.h[j] = __float2bfloat16(sm.p.xt[ks * 32 + ((l >> 4) << 3) + j][node]);
            #pragma unroll
            for (int ot = 0; ot < 8; ++ot)
                acc[ot] = __builtin_amdgcn_mfma_f32_16x16x32_bf16(a.v, wf[ks][ot].v, acc[ot], 0, 0, 0);
        }
        size_t base = ((size_t)n0 + (w << 4)) * 128;
        #pragma unroll
        for (int ot = 0; ot < 8; ++ot)
            #pragma unroll
            for (int r = 0; r < 4; ++r) {
                int nd = ((l >> 4) << 2) + r;
                FGb[base + (size_t)nd * 128 + ot * 16 + (l & 15)] = __float2bfloat16(acc[ot][r]);
            }
        asm volatile("s_waitcnt vmcnt(0)");   // stores resident in local L2
        __syncthreads();
        if (t == 0) atomicAdd(&prod_done[b], 1u);
    }

    // ---- per-XCD barrier: batch b fully produced (atomic RMW spin, no fence) ----
    if (t == 0) {
        while (atomicAdd(&prod_done[b], 0u) < 64u) __builtin_amdgcn_s_sleep(32);
    }
    __syncthreads();

    // ================= consumer: batch b's gather+max, tiles of 32 nodes =================
    const int* srcp = ei + (size_t)b * NN * KK;      // ei[0][b]
    const uint2* FGq = (const uint2*)FGb;            // 32 uint2 per 256B row
    float* ob = out + (size_t)b * OO * NN;

    for (;;) {
        __syncthreads();
        if (t == 0) s_t = atomicAdd(&cons_ctr[b], 1u);
        __syncthreads();
        unsigned tt = s_t;
        if (tt >= 128u) break;
        int n0 = (int)tt << 5;
        int nb = n0 + (w << 3);
        int eg = l >> 4, c = l & 15;

        int idxv[8];
        #pragma unroll
        for (int i = 0; i < 8; ++i) idxv[i] = srcp[(nb + i) * KK + c];

        uint2 fv[2];
        #pragma unroll
        for (int p = 0; p < 2; ++p) fv[p] = FGq[(size_t)(nb + (p << 2) + eg) * 32 + c];

        uint2 g[8][4];
        #pragma unroll
        for (int i = 0; i < 8; ++i)
            #pragma unroll
            for (int q = 0; q < 4; ++q) {
                int vk = __shfl(idxv[i], (q << 2) | eg);
                g[i][q] = FGq[(size_t)vk * 32 + 16 + c];   // LOCAL L2 hit
            }

        #pragma unroll
        for (int i = 0; i < 8; ++i) {
            float m0 = -3.4e38f, m1 = -3.4e38f, m2 = -3.4e38f, m3 = -3.4e38f;
            #pragma unroll
            for (int q = 0; q < 4; ++q) {
                m0 = fmaxf(m0, __uint_as_float(g[i][q].x << 16));
                m1 = fmaxf(m1, __uint_as_float(g[i][q].x & 0xffff0000u));
                m2 = fmaxf(m2, __uint_as_float(g[i][q].y << 16));
                m3 = fmaxf(m3, __uint_as_float(g[i][q].y & 0xffff0000u));
            }
            m0 = fmaxf(m0, __shfl_xor(m0, 16)); m0 = fmaxf(m0, __shfl_xor(m0, 32));
            m1 = fmaxf(m1, __shfl_xor(m1, 16)); m1 = fmaxf(m1, __shfl_xor(m1, 32));
            m2 = fmaxf(m2, __shfl_xor(m2, 16)); m2 = fmaxf(m2, __shfl_xor(m2, 32));
            m3 = fmaxf(m3, __shfl_xor(m3, 16)); m3 = fmaxf(m3, __shfl_xor(m3, 32));
            if (eg == (i & 3)) {
                uint2 f = fv[i >> 2];
                int nl = (w << 3) + i;
                sm.ot[4 * c + 0][nl] = fmaxf(__uint_as_float(f.x << 16) + m0, 0.0f);
                sm.ot[4 * c + 1][nl] = fmaxf(__uint_as_float(f.x & 0xffff0000u) + m1, 0.0f);
                sm.ot[4 * c + 2][nl] = fmaxf(__uint_as_float(f.y << 16) + m2, 0.0f);
                sm.ot[4 * c + 3][nl] = fmaxf(__uint_as_float(f.y & 0xffff0000u) + m3, 0.0f);
            }
        }
        __syncthreads();
        #pragma unroll
        for (int it = 0; it < 8; ++it) {
            int idx = it * 256 + t, o = idx >> 5, nn = idx & 31;
            ob[(size_t)o * NN + n0 + nn] = sm.ot[o][nn];
        }
    }
}

extern "C" void kernel_launch(void* const* d_in, const int* in_sizes, int n_in,
                              void* d_out, int out_size, void* d_ws, size_t ws_size,
                              hipStream_t stream) {
    const float* x    = (const float*)d_in[0];   // [B,C,N,1] f32
    const int*   ei   = (const int*)d_in[1];     // [2,B,N,K] i32
    const float* W    = (const float*)d_in[2];   // [128,64] f32
    const float* bias = (const float*)d_in[3];   // [64] f32
    float* out = (float*)d_out;                  // [B,O,N,1] f32

    __hip_bfloat16* FG = (__hip_bfloat16*)d_ws;                  // 8 MB
    unsigned* ctr = (unsigned*)((char*)d_ws + FG_BYTES);         // 128 B counters

    hipMemsetAsync(ctr, 0, 128, stream);                         // graph-safe, every call
    hipLaunchKernelGGL(edgeconv_xcd, dim3(GRID), dim3(256), 0, stream,
                       x, ei, W, bias, out, FG, ctr);
}

// Round 13
// 24.405 us; speedup vs baseline: 3.1677x; 3.1677x over previous
//
#include <hip/hip_runtime.h>
#include <hip/hip_bf16.h>

// EdgeConv: B=8, C=64, N=4096, K=16, O=64
// out[n] = relu(F[n] + max_k G[src[n,k]]);  F = x@(Wa-Wb)+bias, G = x@Wb.
// k1 (g_gemm): G[B*N][64] bf16 only (4 MB).
// k2 (gather_max): computes F itself (4 MFMAs/wave from x, LDS-held) + G gathers.
//
// Locked-in config (12 rounds of evidence):
//  - two plain dispatches; NO coop launch / XCD swizzle / __threadfence / atomic
//    spin barriers (each costs 3-5x: R4/5=113us, R7/10=60-88us, R12=77us)
//  - gather floor is the L2 random-line request ceiling (~31 req/ns device-wide;
//    R8/R9/R11 instruction/locality/MLP changes all null at 24us) -> only lever
//    left is removing non-gather traffic (this round: F never hits global).

#define BB 8
#define CC 64
#define NN 4096
#define KK 16
#define OO 64

typedef __bf16 bf16x8 __attribute__((ext_vector_type(8)));
typedef float f32x4 __attribute__((ext_vector_type(4)));

union Frag { int4 i; bf16x8 v; };
union PackA { bf16x8 v; __hip_bfloat16 h[8]; };

// ---------------- k1: G = x@Wb -> [B*N][64] bf16 ----------------
// Block: 64 nodes of one batch. 4 waves x 16 nodes, 8 MFMAs each.
__global__ __launch_bounds__(256, 3) void g_gemm(
    const float* __restrict__ x, const float* __restrict__ W,
    __hip_bfloat16* __restrict__ G) {
    __shared__ float xt[64][65];      // [c][node] f32
    __shared__ int4 wfl[8][64];       // Wb B-frags: [ks*4+ot][lane]

    int t = threadIdx.x, w = t >> 6, l = t & 63;
    int b = blockIdx.x >> 6;
    int n0 = (blockIdx.x & 63) << 6;

    const float* xb = x + (size_t)b * CC * NN;
    #pragma unroll
    for (int it = 0; it < 4; ++it) {
        int idx = it * 256 + t, c = idx >> 4, q = idx & 15;
        float4 v = *(const float4*)(xb + (size_t)c * NN + n0 + q * 4);
        xt[c][q * 4 + 0] = v.x; xt[c][q * 4 + 1] = v.y;
        xt[c][q * 4 + 2] = v.z; xt[c][q * 4 + 3] = v.w;
    }
    {   // Wb fragments only
        __hip_bfloat16* wlu = (__hip_bfloat16*)wfl;
        int o = t & 63, h = t >> 6;
        #pragma unroll
        for (int kk = 0; kk < 16; ++kk) {
            int k = h * 16 + kk;
            float wb = W[(64 + k) * OO + o];
            int gq = (k >> 3) & 3, j = k & 7, ks = k >> 5;
            int lane = (gq << 4) | (o & 15);
            int fs = ks * 4 + (o >> 4);
            wlu[((fs * 64 + lane) << 3) | j] = __float2bfloat16(wb);
        }
    }
    __syncthreads();

    Frag wf[2][4];
    #pragma unroll
    for (int ks = 0; ks < 2; ++ks)
        #pragma unroll
        for (int ot = 0; ot < 4; ++ot)
            wf[ks][ot].i = wfl[ks * 4 + ot][l];

    f32x4 acc[4];
    #pragma unroll
    for (int ot = 0; ot < 4; ++ot) acc[ot] = f32x4{0.f, 0.f, 0.f, 0.f};

    int node = (w << 4) + (l & 15);
    #pragma unroll
    for (int ks = 0; ks < 2; ++ks) {
        PackA a;
        #pragma unroll
        for (int j = 0; j < 8; ++j)
            a.h[j] = __float2bfloat16(xt[ks * 32 + ((l >> 4) << 3) + j][node]);
        #pragma unroll
        for (int ot = 0; ot < 4; ++ot)
            acc[ot] = __builtin_amdgcn_mfma_f32_16x16x32_bf16(a.v, wf[ks][ot].v, acc[ot], 0, 0, 0);
    }

    // D: col = lane&15, row = (lane>>4)*4 + r
    size_t base = ((size_t)b * NN + n0 + (w << 4)) * 64;
    #pragma unroll
    for (int ot = 0; ot < 4; ++ot)
        #pragma unroll
        for (int r = 0; r < 4; ++r) {
            int nd = ((l >> 4) << 2) + r;
            G[base + (size_t)nd * 64 + ot * 16 + (l & 15)] = __float2bfloat16(acc[ot][r]);
        }
}

// ---------------- k2: F in-kernel + gather-max ----------------
// Block: 32 dst nodes. Phase A: F = x@(Wa-Wb)+bias via 4 MFMAs/wave -> LDS.
// Phase B: 32 uint2 G-gathers/wave upfront, fmax reduce, combine with F, out.
__global__ __launch_bounds__(256, 4) void gather_max(
    const float* __restrict__ x, const int* __restrict__ ei,
    const float* __restrict__ W, const float* __restrict__ bias,
    const uint2* __restrict__ Gq, float* __restrict__ out) {
    __shared__ union { float xt[64][33]; float ot_[64][33]; } sm;  // 8.4 KB, time-shared
    __shared__ int4 wfl[8][64];       // Wa-Wb B-frags, 8 KB
    __shared__ float Fl[32][65];      // F rows f32, 8.3 KB

    int t = threadIdx.x, w = t >> 6, l = t & 63;
    int b = blockIdx.x >> 7;
    int n0 = (blockIdx.x & 127) << 5;

    // ---- load x rows of own 32 nodes (coalesced along n) ----
    const float* xb = x + (size_t)b * CC * NN;
    #pragma unroll
    for (int it = 0; it < 8; ++it) {
        int idx = it * 256 + t, c = idx >> 5, nn = idx & 31;
        sm.xt[c][nn] = xb[(size_t)c * NN + n0 + nn];
    }
    // ---- (Wa-Wb) fragments ----
    {
        __hip_bfloat16* wlu = (__hip_bfloat16*)wfl;
        int o = t & 63, h = t >> 6;
        #pragma unroll
        for (int kk = 0; kk < 16; ++kk) {
            int k = h * 16 + kk;
            float v = W[k * OO + o] - W[(64 + k) * OO + o];
            int gq = (k >> 3) & 3, j = k & 7, ks = k >> 5;
            int lane = (gq << 4) | (o & 15);
            int fs = ks * 4 + (o >> 4);
            wlu[((fs * 64 + lane) << 3) | j] = __float2bfloat16(v);
        }
    }
    // prefetch edge indices early (hide behind F phase)
    const int* srcp = ei + (size_t)b * NN * KK;
    int nb = n0 + (w << 3);
    int eg = l >> 4, c = l & 15;
    int idxv[8];
    #pragma unroll
    for (int i = 0; i < 8; ++i) idxv[i] = srcp[(nb + i) * KK + c];
    __syncthreads();

    // ---- phase A: F for 32 nodes. wave w: nodes (w&1)*16.., o-tiles (w>>1)*2..+1 ----
    {
        int ng = (w & 1) << 4;         // node group base
        int ob = (w >> 1) << 1;        // first o-tile
        Frag wfA[2][2];
        #pragma unroll
        for (int ks = 0; ks < 2; ++ks)
            #pragma unroll
            for (int oo = 0; oo < 2; ++oo)
                wfA[ks][oo].i = wfl[ks * 4 + ob + oo][l];
        f32x4 acc[2];
        #pragma unroll
        for (int oo = 0; oo < 2; ++oo) {
            float bv = bias[(ob + oo) * 16 + (l & 15)];
            acc[oo] = f32x4{bv, bv, bv, bv};
        }
        #pragma unroll
        for (int ks = 0; ks < 2; ++ks) {
            PackA a;
            #pragma unroll
            for (int j = 0; j < 8; ++j)
                a.h[j] = __float2bfloat16(sm.xt[ks * 32 + ((l >> 4) << 3) + j][ng + (l & 15)]);
            #pragma unroll
            for (int oo = 0; oo < 2; ++oo)
                acc[oo] = __builtin_amdgcn_mfma_f32_16x16x32_bf16(a.v, wfA[ks][oo].v, acc[oo], 0, 0, 0);
        }
        #pragma unroll
        for (int oo = 0; oo < 2; ++oo)
            #pragma unroll
            for (int r = 0; r < 4; ++r)
                Fl[ng + ((l >> 4) << 2) + r][(ob + oo) * 16 + (l & 15)] = acc[oo][r];
    }
    __syncthreads();   // Fl ready; xt dead -> sm reusable as otile

    // ---- phase B: G gathers (32 uint2 upfront = max MLP) ----
    size_t bbase = (size_t)b * NN;
    uint2 g[8][4];
    #pragma unroll
    for (int i = 0; i < 8; ++i)
        #pragma unroll
        for (int q = 0; q < 4; ++q) {
            int vk = __shfl(idxv[i], (q << 2) | eg);
            g[i][q] = Gq[((size_t)bbase + vk) * 16 + c];   // G row = 16 uint2
        }

    #pragma unroll
    for (int i = 0; i < 8; ++i) {
        float m0 = -3.4e38f, m1 = -3.4e38f, m2 = -3.4e38f, m3 = -3.4e38f;
        #pragma unroll
        for (int q = 0; q < 4; ++q) {
            m0 = fmaxf(m0, __uint_as_float(g[i][q].x << 16));
            m1 = fmaxf(m1, __uint_as_float(g[i][q].x & 0xffff0000u));
            m2 = fmaxf(m2, __uint_as_float(g[i][q].y << 16));
            m3 = fmaxf(m3, __uint_as_float(g[i][q].y & 0xffff0000u));
        }
        m0 = fmaxf(m0, __shfl_xor(m0, 16)); m0 = fmaxf(m0, __shfl_xor(m0, 32));
        m1 = fmaxf(m1, __shfl_xor(m1, 16)); m1 = fmaxf(m1, __shfl_xor(m1, 32));
        m2 = fmaxf(m2, __shfl_xor(m2, 16)); m2 = fmaxf(m2, __shfl_xor(m2, 32));
        m3 = fmaxf(m3, __shfl_xor(m3, 16)); m3 = fmaxf(m3, __shfl_xor(m3, 32));
        if (eg == (i & 3)) {
            int nl = (w << 3) + i;
            sm.ot_[4 * c + 0][nl] = fmaxf(Fl[nl][4 * c + 0] + m0, 0.0f);
            sm.ot_[4 * c + 1][nl] = fmaxf(Fl[nl][4 * c + 1] + m1, 0.0f);
            sm.ot_[4 * c + 2][nl] = fmaxf(Fl[nl][4 * c + 2] + m2, 0.0f);
            sm.ot_[4 * c + 3][nl] = fmaxf(Fl[nl][4 * c + 3] + m3, 0.0f);
        }
    }
    __syncthreads();

    float* ob2 = out + (size_t)b * OO * NN;
    #pragma unroll
    for (int it = 0; it < 8; ++it) {
        int idx = it * 256 + t, o = idx >> 5, nn = idx & 31;
        ob2[(size_t)o * NN + n0 + nn] = sm.ot_[o][nn];   // coalesced 128B rows
    }
}

extern "C" void kernel_launch(void* const* d_in, const int* in_sizes, int n_in,
                              void* d_out, int out_size, void* d_ws, size_t ws_size,
                              hipStream_t stream) {
    const float* x    = (const float*)d_in[0];   // [B,C,N,1] f32
    const int*   ei   = (const int*)d_in[1];     // [2,B,N,K] i32
    const float* W    = (const float*)d_in[2];   // [128,64] f32
    const float* bias = (const float*)d_in[3];   // [64] f32
    float* out = (float*)d_out;                  // [B,O,N,1] f32

    __hip_bfloat16* G = (__hip_bfloat16*)d_ws;   // [B*N][64] bf16 = 4 MB

    hipLaunchKernelGGL(g_gemm, dim3(BB * (NN / 64)), dim3(256), 0, stream, x, W, G);
    hipLaunchKernelGGL(gather_max, dim3(BB * (NN / 32)), dim3(256), 0, stream,
                       x, ei, W, bias, (const uint2*)G, out);
}